// Round 1
// baseline (2230.142 us; speedup 1.0000x reference)
//
#include <hip/hip_runtime.h>
#include <hip/hip_bf16.h>

#define DIM 128
#define HIDDEN 384
#define BATCH 4
#define NDATA 100000
#define NEDGE 200000
#define NLOG 4096
#define TM 32

// ---------------------------------------------------------------------------
// CSR build: histogram -> scan -> scatter (edge order within a segment is
// nondeterministic; product rounding diff ~49 ulp relative, far below 2% tol)
// ---------------------------------------------------------------------------
__global__ void zero_counts_kernel(int* __restrict__ counts) {
  int i = blockIdx.x * blockDim.x + threadIdx.x;
  if (i < NLOG) counts[i] = 0;
}

__global__ void count_kernel(const int* __restrict__ dst, int* __restrict__ counts) {
  int e = blockIdx.x * blockDim.x + threadIdx.x;
  if (e < NEDGE) atomicAdd(&counts[dst[e]], 1);
}

__global__ __launch_bounds__(1024) void scan_kernel(const int* __restrict__ counts,
                                                    int* __restrict__ offsets,
                                                    int* __restrict__ cursor) {
  __shared__ int sdata[1024];
  const int t = threadIdx.x;
  const int c0 = counts[4 * t + 0];
  const int c1 = counts[4 * t + 1];
  const int c2 = counts[4 * t + 2];
  const int c3 = counts[4 * t + 3];
  const int s = c0 + c1 + c2 + c3;
  sdata[t] = s;
  __syncthreads();
  for (int off = 1; off < 1024; off <<= 1) {
    int vv = (t >= off) ? sdata[t - off] : 0;
    __syncthreads();
    sdata[t] += vv;
    __syncthreads();
  }
  const int excl = sdata[t] - s;
  const int o0 = excl, o1 = o0 + c0, o2 = o1 + c1, o3 = o2 + c2;
  offsets[4 * t + 0] = o0;
  offsets[4 * t + 1] = o1;
  offsets[4 * t + 2] = o2;
  offsets[4 * t + 3] = o3;
  cursor[4 * t + 0] = o0;
  cursor[4 * t + 1] = o1;
  cursor[4 * t + 2] = o2;
  cursor[4 * t + 3] = o3;
  if (t == 1023) offsets[NLOG] = o3 + c3;
}

__global__ void scatter_kernel(const int* __restrict__ src, const int* __restrict__ dst,
                               int* __restrict__ cursor, int* __restrict__ sorted_src) {
  int e = blockIdx.x * blockDim.x + threadIdx.x;
  if (e < NEDGE) {
    int d = dst[e];
    int pos = atomicAdd(&cursor[d], 1);
    sorted_src[pos] = src[e];
  }
}

// ---------------------------------------------------------------------------
// segment product: one 128-thread block per (segment, batch); 4 independent
// partial products for ILP over the dependent multiply chain.
// ---------------------------------------------------------------------------
__global__ __launch_bounds__(128) void prod_kernel(const float* __restrict__ v_act,
                                                   const int* __restrict__ offsets,
                                                   const int* __restrict__ sorted_src,
                                                   float* __restrict__ l) {
  const int s = blockIdx.x;
  const int b = blockIdx.y;
  const int t = threadIdx.x;
  const int beg = offsets[s];
  const int end = offsets[s + 1];
  const float* base = v_act + (size_t)b * NDATA * DIM + t;
  float p0 = 1.f, p1 = 1.f, p2 = 1.f, p3 = 1.f;
  int e = beg;
  for (; e + 4 <= end; e += 4) {
    const int i0 = sorted_src[e + 0];
    const int i1 = sorted_src[e + 1];
    const int i2 = sorted_src[e + 2];
    const int i3 = sorted_src[e + 3];
    p0 *= base[(size_t)i0 * DIM];
    p1 *= base[(size_t)i1 * DIM];
    p2 *= base[(size_t)i2 * DIM];
    p3 *= base[(size_t)i3 * DIM];
  }
  for (; e < end; ++e) p0 *= base[(size_t)sorted_src[e] * DIM];
  l[((size_t)b * NLOG + s) * DIM + t] = (p0 * p1) * (p2 * p3);
}

// ---------------------------------------------------------------------------
// Fused FFN kernels (fp32 VALU, 32-row tile, 4x4 register blocking).
// LDS: xn 16KB + gs 48KB = 64KB -> 2 blocks/CU.
// ---------------------------------------------------------------------------
__global__ __launch_bounds__(256) void ffn1_kernel(
    const float* __restrict__ v, const float* __restrict__ rmsw,
    const float* __restrict__ w1, const float* __restrict__ w2,
    const float* __restrict__ w3, float* __restrict__ v_act) {
  __shared__ alignas(16) float xn[TM][DIM];
  __shared__ alignas(16) float gs[TM][HIDDEN];
  const int t = threadIdx.x;
  const size_t row0 = (size_t)blockIdx.x * TM;

  {  // Phase A: load + rmsnorm, 8 lanes per row
    const int r = t >> 3;
    const int c0 = (t & 7) * 16;
    const float* vr = v + (row0 + r) * DIM + c0;
    alignas(16) float av[16];
    *(float4*)(av + 0) = *(const float4*)(vr + 0);
    *(float4*)(av + 4) = *(const float4*)(vr + 4);
    *(float4*)(av + 8) = *(const float4*)(vr + 8);
    *(float4*)(av + 12) = *(const float4*)(vr + 12);
    float ss = 0.f;
#pragma unroll
    for (int i = 0; i < 16; ++i) ss += av[i] * av[i];
    ss += __shfl_xor(ss, 1);
    ss += __shfl_xor(ss, 2);
    ss += __shfl_xor(ss, 4);
    const float scale = rsqrtf(ss * (1.0f / DIM) + 1e-5f);
    alignas(16) float ov[16];
#pragma unroll
    for (int i = 0; i < 16; ++i) ov[i] = av[i] * scale * rmsw[c0 + i];
    *(float4*)&xn[r][c0 + 0] = *(float4*)(ov + 0);
    *(float4*)&xn[r][c0 + 4] = *(float4*)(ov + 4);
    *(float4*)&xn[r][c0 + 8] = *(float4*)(ov + 8);
    *(float4*)&xn[r][c0 + 12] = *(float4*)(ov + 12);
  }
  __syncthreads();

  const int r0 = (t >> 5) * 4;
  const int j0 = (t & 31) * 4;

  // Phase B: h1 = X@W1, h3 = X@W3 per 128-wide hidden chunk; gs = silu(h1)*h3
  for (int c = 0; c < 3; ++c) {
    const float* w1p = w1 + c * 128 + j0;
    const float* w3p = w3 + c * 128 + j0;
    float acc1[4][4] = {{0.f}};
    float acc3[4][4] = {{0.f}};
    for (int k = 0; k < DIM; k += 4) {
      alignas(16) float xr[4][4];
#pragma unroll
      for (int i = 0; i < 4; ++i) *(float4*)xr[i] = *(const float4*)&xn[r0 + i][k];
#pragma unroll
      for (int kk = 0; kk < 4; ++kk) {
        const float4 wv1 = *(const float4*)(w1p + (size_t)(k + kk) * HIDDEN);
        const float4 wv3 = *(const float4*)(w3p + (size_t)(k + kk) * HIDDEN);
#pragma unroll
        for (int i = 0; i < 4; ++i) {
          const float x = xr[i][kk];
          acc1[i][0] = fmaf(x, wv1.x, acc1[i][0]);
          acc1[i][1] = fmaf(x, wv1.y, acc1[i][1]);
          acc1[i][2] = fmaf(x, wv1.z, acc1[i][2]);
          acc1[i][3] = fmaf(x, wv1.w, acc1[i][3]);
          acc3[i][0] = fmaf(x, wv3.x, acc3[i][0]);
          acc3[i][1] = fmaf(x, wv3.y, acc3[i][1]);
          acc3[i][2] = fmaf(x, wv3.z, acc3[i][2]);
          acc3[i][3] = fmaf(x, wv3.w, acc3[i][3]);
        }
      }
    }
#pragma unroll
    for (int i = 0; i < 4; ++i) {
      alignas(16) float o[4];
#pragma unroll
      for (int j = 0; j < 4; ++j) {
        const float h1 = acc1[i][j];
        const float h3 = acc3[i][j];
        o[j] = h1 * (1.0f / (1.0f + __expf(-h1))) * h3;
      }
      *(float4*)&gs[r0 + i][c * 128 + j0] = *(float4*)o;
    }
  }
  __syncthreads();

  // Phase C: F = G@W2; epilogue tanh(F + v)
  float acc[4][4] = {{0.f}};
  const float* w2p = w2 + j0;
  for (int k = 0; k < HIDDEN; k += 4) {
    alignas(16) float gr[4][4];
#pragma unroll
    for (int i = 0; i < 4; ++i) *(float4*)gr[i] = *(const float4*)&gs[r0 + i][k];
#pragma unroll
    for (int kk = 0; kk < 4; ++kk) {
      const float4 wv = *(const float4*)(w2p + (size_t)(k + kk) * DIM);
#pragma unroll
      for (int i = 0; i < 4; ++i) {
        const float gg = gr[i][kk];
        acc[i][0] = fmaf(gg, wv.x, acc[i][0]);
        acc[i][1] = fmaf(gg, wv.y, acc[i][1]);
        acc[i][2] = fmaf(gg, wv.z, acc[i][2]);
        acc[i][3] = fmaf(gg, wv.w, acc[i][3]);
      }
    }
  }
#pragma unroll
  for (int i = 0; i < 4; ++i) {
    const float4 vv = *(const float4*)(v + (row0 + r0 + i) * DIM + j0);
    float4 o;
    o.x = tanhf(acc[i][0] + vv.x);
    o.y = tanhf(acc[i][1] + vv.y);
    o.z = tanhf(acc[i][2] + vv.z);
    o.w = tanhf(acc[i][3] + vv.w);
    *(float4*)(v_act + (row0 + r0 + i) * DIM + j0) = o;
  }
}

__global__ __launch_bounds__(256) void ffn2_kernel(
    const float* __restrict__ lin, const float* __restrict__ rmsw,
    const float* __restrict__ w1, const float* __restrict__ w2,
    const float* __restrict__ w3, const float* __restrict__ wout,
    const float* __restrict__ bout, float* __restrict__ out) {
  __shared__ alignas(16) float xn[TM][DIM];
  __shared__ alignas(16) float gs[TM][HIDDEN];
  const int t = threadIdx.x;
  const size_t row0 = (size_t)blockIdx.x * TM;

  {  // Phase A
    const int r = t >> 3;
    const int c0 = (t & 7) * 16;
    const float* vr = lin + (row0 + r) * DIM + c0;
    alignas(16) float av[16];
    *(float4*)(av + 0) = *(const float4*)(vr + 0);
    *(float4*)(av + 4) = *(const float4*)(vr + 4);
    *(float4*)(av + 8) = *(const float4*)(vr + 8);
    *(float4*)(av + 12) = *(const float4*)(vr + 12);
    float ss = 0.f;
#pragma unroll
    for (int i = 0; i < 16; ++i) ss += av[i] * av[i];
    ss += __shfl_xor(ss, 1);
    ss += __shfl_xor(ss, 2);
    ss += __shfl_xor(ss, 4);
    const float scale = rsqrtf(ss * (1.0f / DIM) + 1e-5f);
    alignas(16) float ov[16];
#pragma unroll
    for (int i = 0; i < 16; ++i) ov[i] = av[i] * scale * rmsw[c0 + i];
    *(float4*)&xn[r][c0 + 0] = *(float4*)(ov + 0);
    *(float4*)&xn[r][c0 + 4] = *(float4*)(ov + 4);
    *(float4*)&xn[r][c0 + 8] = *(float4*)(ov + 8);
    *(float4*)&xn[r][c0 + 12] = *(float4*)(ov + 12);
  }
  __syncthreads();

  const int r0 = (t >> 5) * 4;
  const int j0 = (t & 31) * 4;

  // Phase B
  for (int c = 0; c < 3; ++c) {
    const float* w1p = w1 + c * 128 + j0;
    const float* w3p = w3 + c * 128 + j0;
    float acc1[4][4] = {{0.f}};
    float acc3[4][4] = {{0.f}};
    for (int k = 0; k < DIM; k += 4) {
      alignas(16) float xr[4][4];
#pragma unroll
      for (int i = 0; i < 4; ++i) *(float4*)xr[i] = *(const float4*)&xn[r0 + i][k];
#pragma unroll
      for (int kk = 0; kk < 4; ++kk) {
        const float4 wv1 = *(const float4*)(w1p + (size_t)(k + kk) * HIDDEN);
        const float4 wv3 = *(const float4*)(w3p + (size_t)(k + kk) * HIDDEN);
#pragma unroll
        for (int i = 0; i < 4; ++i) {
          const float x = xr[i][kk];
          acc1[i][0] = fmaf(x, wv1.x, acc1[i][0]);
          acc1[i][1] = fmaf(x, wv1.y, acc1[i][1]);
          acc1[i][2] = fmaf(x, wv1.z, acc1[i][2]);
          acc1[i][3] = fmaf(x, wv1.w, acc1[i][3]);
          acc3[i][0] = fmaf(x, wv3.x, acc3[i][0]);
          acc3[i][1] = fmaf(x, wv3.y, acc3[i][1]);
          acc3[i][2] = fmaf(x, wv3.z, acc3[i][2]);
          acc3[i][3] = fmaf(x, wv3.w, acc3[i][3]);
        }
      }
    }
#pragma unroll
    for (int i = 0; i < 4; ++i) {
      alignas(16) float o[4];
#pragma unroll
      for (int j = 0; j < 4; ++j) {
        const float h1 = acc1[i][j];
        const float h3 = acc3[i][j];
        o[j] = h1 * (1.0f / (1.0f + __expf(-h1))) * h3;
      }
      *(float4*)&gs[r0 + i][c * 128 + j0] = *(float4*)o;
    }
  }
  __syncthreads();

  // Phase C + residual; stash f into xn (free after phase B)
  float acc[4][4] = {{0.f}};
  const float* w2p = w2 + j0;
  for (int k = 0; k < HIDDEN; k += 4) {
    alignas(16) float gr[4][4];
#pragma unroll
    for (int i = 0; i < 4; ++i) *(float4*)gr[i] = *(const float4*)&gs[r0 + i][k];
#pragma unroll
    for (int kk = 0; kk < 4; ++kk) {
      const float4 wv = *(const float4*)(w2p + (size_t)(k + kk) * DIM);
#pragma unroll
      for (int i = 0; i < 4; ++i) {
        const float gg = gr[i][kk];
        acc[i][0] = fmaf(gg, wv.x, acc[i][0]);
        acc[i][1] = fmaf(gg, wv.y, acc[i][1]);
        acc[i][2] = fmaf(gg, wv.z, acc[i][2]);
        acc[i][3] = fmaf(gg, wv.w, acc[i][3]);
      }
    }
  }
#pragma unroll
  for (int i = 0; i < 4; ++i) {
    const float4 lv = *(const float4*)(lin + (row0 + r0 + i) * DIM + j0);
    float4 o;
    o.x = acc[i][0] + lv.x;
    o.y = acc[i][1] + lv.y;
    o.z = acc[i][2] + lv.z;
    o.w = acc[i][3] + lv.w;
    *(float4*)&xn[r0 + i][j0] = o;
  }
  __syncthreads();

  // final readout: out = f @ wout + bout, 8 lanes per row
  {
    const int r = t >> 3;
    const int c0 = (t & 7) * 16;
    float s = 0.f;
#pragma unroll
    for (int i = 0; i < 16; i += 4) {
      const float4 f = *(const float4*)&xn[r][c0 + i];
      const float4 w = *(const float4*)(wout + c0 + i);
      s += f.x * w.x + f.y * w.y + f.z * w.z + f.w * w.w;
    }
    s += __shfl_xor(s, 1);
    s += __shfl_xor(s, 2);
    s += __shfl_xor(s, 4);
    if ((t & 7) == 0) out[row0 + r] = s + bout[0];
  }
}

// ---------------------------------------------------------------------------
extern "C" void kernel_launch(void* const* d_in, const int* in_sizes, int n_in,
                              void* d_out, int out_size, void* d_ws, size_t ws_size,
                              hipStream_t stream) {
  const float* v = (const float*)d_in[0];
  const int* data_src = (const int*)d_in[1];
  const int* data_dst = (const int*)d_in[2];
  // d_in[3] = num_logical (constant 4096, unused)
  const float* rms1_w = (const float*)d_in[4];
  const float* w1a = (const float*)d_in[5];
  const float* w2a = (const float*)d_in[6];
  const float* w3a = (const float*)d_in[7];
  const float* rms2_w = (const float*)d_in[8];
  const float* w1b = (const float*)d_in[9];
  const float* w2b = (const float*)d_in[10];
  const float* w3b = (const float*)d_in[11];
  const float* wout = (const float*)d_in[12];
  const float* bout = (const float*)d_in[13];
  float* out = (float*)d_out;

  // workspace layout (256B aligned), total ~214 MB
  char* ws = (char*)d_ws;
  size_t off = 0;
  auto take = [&](size_t bytes) -> char* {
    char* p = ws + off;
    off += (bytes + 255) & ~(size_t)255;
    return p;
  };
  float* v_act = (float*)take((size_t)BATCH * NDATA * DIM * 4);
  float* lbuf = (float*)take((size_t)BATCH * NLOG * DIM * 4);
  int* counts = (int*)take(NLOG * 4);
  int* offsets = (int*)take((NLOG + 1) * 4);
  int* cursor = (int*)take(NLOG * 4);
  int* sorted_src = (int*)take(NEDGE * 4);

  // CSR build
  zero_counts_kernel<<<(NLOG + 255) / 256, 256, 0, stream>>>(counts);
  count_kernel<<<(NEDGE + 255) / 256, 256, 0, stream>>>(data_dst, counts);
  scan_kernel<<<1, 1024, 0, stream>>>(counts, offsets, cursor);
  scatter_kernel<<<(NEDGE + 255) / 256, 256, 0, stream>>>(data_src, data_dst, cursor,
                                                          sorted_src);
  // big FFN over all 400k rows
  ffn1_kernel<<<(BATCH * NDATA) / TM, 256, 0, stream>>>(v, rms1_w, w1a, w2a, w3a, v_act);
  // segment products (batch-major grid for L2/L3 locality)
  prod_kernel<<<dim3(NLOG, BATCH), 128, 0, stream>>>(v_act, offsets, sorted_src, lbuf);
  // small FFN + readout
  ffn2_kernel<<<(BATCH * NLOG) / TM, 256, 0, stream>>>(lbuf, rms2_w, w1b, w2b, w3b, wout,
                                                       bout, out);
}

// Round 2
// 784.141 us; speedup vs baseline: 2.8441x; 2.8441x over previous
//
#include <hip/hip_runtime.h>
#include <hip/hip_bf16.h>

#define DIM 128
#define HIDDEN 384
#define BATCH 4
#define NDATA 100000
#define NEDGE 200000
#define NLOG 4096

typedef __bf16 bf16x8 __attribute__((ext_vector_type(8)));
typedef float f32x4 __attribute__((ext_vector_type(4)));
typedef unsigned short u16;
typedef unsigned int u32;

__device__ __forceinline__ u16 f2bf(float f) {
  u32 u = __float_as_uint(f);
  u += 0x7FFFu + ((u >> 16) & 1u);  // RNE; values are finite
  return (u16)(u >> 16);
}
__device__ __forceinline__ bf16x8 as_bf(uint4 u) {
  return __builtin_bit_cast(bf16x8, u);
}

// ---------------------------------------------------------------------------
// CSR build: histogram -> scan -> scatter
// ---------------------------------------------------------------------------
__global__ void zero_counts_kernel(int* __restrict__ counts) {
  int i = blockIdx.x * blockDim.x + threadIdx.x;
  if (i < NLOG) counts[i] = 0;
}

__global__ void count_kernel(const int* __restrict__ dst, int* __restrict__ counts) {
  int e = blockIdx.x * blockDim.x + threadIdx.x;
  if (e < NEDGE) atomicAdd(&counts[dst[e]], 1);
}

__global__ __launch_bounds__(1024) void scan_kernel(const int* __restrict__ counts,
                                                    int* __restrict__ offsets,
                                                    int* __restrict__ cursor) {
  __shared__ int sdata[1024];
  const int t = threadIdx.x;
  const int c0 = counts[4 * t + 0];
  const int c1 = counts[4 * t + 1];
  const int c2 = counts[4 * t + 2];
  const int c3 = counts[4 * t + 3];
  const int s = c0 + c1 + c2 + c3;
  sdata[t] = s;
  __syncthreads();
  for (int off = 1; off < 1024; off <<= 1) {
    int vv = (t >= off) ? sdata[t - off] : 0;
    __syncthreads();
    sdata[t] += vv;
    __syncthreads();
  }
  const int excl = sdata[t] - s;
  const int o0 = excl, o1 = o0 + c0, o2 = o1 + c1, o3 = o2 + c2;
  offsets[4 * t + 0] = o0;
  offsets[4 * t + 1] = o1;
  offsets[4 * t + 2] = o2;
  offsets[4 * t + 3] = o3;
  cursor[4 * t + 0] = o0;
  cursor[4 * t + 1] = o1;
  cursor[4 * t + 2] = o2;
  cursor[4 * t + 3] = o3;
  if (t == 1023) offsets[NLOG] = o3 + c3;
}

__global__ void scatter_kernel(const int* __restrict__ src, const int* __restrict__ dst,
                               int* __restrict__ cursor, int* __restrict__ sorted_src) {
  int e = blockIdx.x * blockDim.x + threadIdx.x;
  if (e < NEDGE) {
    int d = dst[e];
    int pos = atomicAdd(&cursor[d], 1);
    sorted_src[pos] = src[e];
  }
}

// ---------------------------------------------------------------------------
// segment product (fp32, unchanged from R1)
// ---------------------------------------------------------------------------
__global__ __launch_bounds__(128) void prod_kernel(const float* __restrict__ v_act,
                                                   const int* __restrict__ offsets,
                                                   const int* __restrict__ sorted_src,
                                                   float* __restrict__ l) {
  const int s = blockIdx.x;
  const int b = blockIdx.y;
  const int t = threadIdx.x;
  const int beg = offsets[s];
  const int end = offsets[s + 1];
  const float* base = v_act + (size_t)b * NDATA * DIM + t;
  float p0 = 1.f, p1 = 1.f, p2 = 1.f, p3 = 1.f;
  int e = beg;
  for (; e + 4 <= end; e += 4) {
    const int i0 = sorted_src[e + 0];
    const int i1 = sorted_src[e + 1];
    const int i2 = sorted_src[e + 2];
    const int i3 = sorted_src[e + 3];
    p0 *= base[(size_t)i0 * DIM];
    p1 *= base[(size_t)i1 * DIM];
    p2 *= base[(size_t)i2 * DIM];
    p3 *= base[(size_t)i3 * DIM];
  }
  for (; e < end; ++e) p0 *= base[(size_t)sorted_src[e] * DIM];
  l[((size_t)b * NLOG + s) * DIM + t] = (p0 * p1) * (p2 * p3);
}

// ---------------------------------------------------------------------------
// weight convert: fp32 -> bf16, transposed to [N][K] row-major (K contiguous)
// so B-fragment loads (n = lane&15, k = quad*8+j) are 16B contiguous.
// ---------------------------------------------------------------------------
__global__ __launch_bounds__(256) void convert_w_kernel(
    const float* __restrict__ w1a, const float* __restrict__ w3a,
    const float* __restrict__ w2a, const float* __restrict__ w1b,
    const float* __restrict__ w3b, const float* __restrict__ w2b,
    u16* __restrict__ w1Ta, u16* __restrict__ w3Ta, u16* __restrict__ w2Ta,
    u16* __restrict__ w1Tb, u16* __restrict__ w3Tb, u16* __restrict__ w2Tb) {
  const int i = blockIdx.x * 256 + threadIdx.x;  // 0..49151 exact
  const int n1 = i >> 7, k1 = i & 127;           // w1T/w3T: [384][128]
  w1Ta[i] = f2bf(w1a[k1 * HIDDEN + n1]);
  w3Ta[i] = f2bf(w3a[k1 * HIDDEN + n1]);
  w1Tb[i] = f2bf(w1b[k1 * HIDDEN + n1]);
  w3Tb[i] = f2bf(w3b[k1 * HIDDEN + n1]);
  const int n2 = i / HIDDEN, k2 = i - n2 * HIDDEN;  // w2T: [128][384]
  w2Ta[i] = f2bf(w2a[k2 * DIM + n2]);
  w2Tb[i] = f2bf(w2b[k2 * DIM + n2]);
}

// ---------------------------------------------------------------------------
// Fused MFMA FFN: xout = maybe_tanh( ffn(rmsnorm(xin)) + xin )
// 64 rows/block, 256 thr (4 waves). Waves partition N. B-frags in registers
// straight from L2. LDS 64 KB exactly: xn[64][128]bf16 + gs[64][384]bf16,
// both stored in 16B chunks swizzled by (chunk ^ (row&7)) to kill bank
// conflicts without padding.
// MFMA 16x16x32 bf16 layouts (m89/m120): A: m=lane&15, k=quad*8+j;
// B: n=lane&15, k=quad*8+j; C/D: col=lane&15, row=quad*4+reg.
// ---------------------------------------------------------------------------
__global__ __launch_bounds__(256, 2) void ffn_mfma_kernel(
    const float* __restrict__ xin, const float* __restrict__ rmsw,
    const u16* __restrict__ w1T, const u16* __restrict__ w3T,
    const u16* __restrict__ w2T, float* __restrict__ xout, int do_tanh) {
  __shared__ alignas(16) u16 sm[32768];  // 65536 B
  char* const sb = (char*)sm;
  const int t = threadIdx.x;
  const int row0 = blockIdx.x * 64;

  // ---- Phase A: load + rmsnorm -> xn (bf16, swizzled 16B chunks) ----
  {
    const int r = t >> 2;  // 0..63
    const int q = t & 3;   // 32-col slice
    const float* vr = xin + (size_t)(row0 + r) * DIM + q * 32;
    float av[32];
#pragma unroll
    for (int i = 0; i < 8; ++i) *(float4*)(av + 4 * i) = *(const float4*)(vr + 4 * i);
    float ss = 0.f;
#pragma unroll
    for (int i = 0; i < 32; ++i) ss += av[i] * av[i];
    ss += __shfl_xor(ss, 1);
    ss += __shfl_xor(ss, 2);
    const float scale = rsqrtf(ss * (1.0f / DIM) + 1e-5f);
    const int r7 = r & 7;
#pragma unroll
    for (int i = 0; i < 4; ++i) {
      u16 us[8];
#pragma unroll
      for (int j = 0; j < 8; ++j)
        us[j] = f2bf(av[8 * i + j] * scale * rmsw[q * 32 + 8 * i + j]);
      uint4 pk;
      pk.x = (u32)us[0] | ((u32)us[1] << 16);
      pk.y = (u32)us[2] | ((u32)us[3] << 16);
      pk.z = (u32)us[4] | ((u32)us[5] << 16);
      pk.w = (u32)us[6] | ((u32)us[7] << 16);
      const int c = q * 4 + i;  // 16B chunk index 0..15
      *(uint4*)(sb + r * 256 + ((c ^ r7) << 4)) = pk;
    }
  }
  __syncthreads();

  const int wv = t >> 6;
  const int lane = t & 63;
  const int m16 = lane & 15;
  const int quad = lane >> 4;
  const int m7 = m16 & 7;

  // ---- GEMM1: xn @ {W1,W3}; gs = silu(h1)*h3 (bf16, swizzled) ----
#pragma unroll 1
  for (int c = 0; c < 3; ++c) {
    const int n0 = (wv + 4 * c) * 32;
    uint4 b1[2][4], b3[2][4];
#pragma unroll
    for (int nt = 0; nt < 2; ++nt) {
      const int nrow = n0 + nt * 16 + m16;
#pragma unroll
      for (int ks = 0; ks < 4; ++ks) {
        const size_t off = (size_t)nrow * DIM + ks * 32 + quad * 8;
        b1[nt][ks] = *(const uint4*)(w1T + off);
        b3[nt][ks] = *(const uint4*)(w3T + off);
      }
    }
#pragma unroll 1
    for (int mt = 0; mt < 4; ++mt) {
      uint4 afr[4];
#pragma unroll
      for (int ks = 0; ks < 4; ++ks)
        afr[ks] = *(const uint4*)(sb + (mt * 16 + m16) * 256 +
                                  ((((ks << 2) | quad) ^ m7) << 4));
      f32x4 acc1[2] = {{0.f, 0.f, 0.f, 0.f}, {0.f, 0.f, 0.f, 0.f}};
      f32x4 acc3[2] = {{0.f, 0.f, 0.f, 0.f}, {0.f, 0.f, 0.f, 0.f}};
#pragma unroll
      for (int ks = 0; ks < 4; ++ks) {
        const bf16x8 a = as_bf(afr[ks]);
#pragma unroll
        for (int nt = 0; nt < 2; ++nt) {
          acc1[nt] = __builtin_amdgcn_mfma_f32_16x16x32_bf16(a, as_bf(b1[nt][ks]),
                                                             acc1[nt], 0, 0, 0);
          acc3[nt] = __builtin_amdgcn_mfma_f32_16x16x32_bf16(a, as_bf(b3[nt][ks]),
                                                             acc3[nt], 0, 0, 0);
        }
      }
#pragma unroll
      for (int nt = 0; nt < 2; ++nt) {
        const int n = n0 + nt * 16 + m16;
        const int cch = n >> 3, o = n & 7;
#pragma unroll
        for (int r = 0; r < 4; ++r) {
          const float h1 = acc1[nt][r], h3 = acc3[nt][r];
          const float g = h1 * (1.0f / (1.0f + __expf(-h1))) * h3;
          const int row = mt * 16 + quad * 4 + r;
          *(u16*)(sb + 16384 + row * 768 + ((cch ^ (row & 7)) << 4) + o * 2) = f2bf(g);
        }
      }
    }
  }
  __syncthreads();

  // ---- GEMM2: gs @ W2 (+residual, optional tanh) -> xout ----
  f32x4 acc[4][2];
#pragma unroll
  for (int mt = 0; mt < 4; ++mt)
#pragma unroll
    for (int nt = 0; nt < 2; ++nt) acc[mt][nt] = {0.f, 0.f, 0.f, 0.f};

#pragma unroll 1
  for (int kh = 0; kh < 2; ++kh) {
    uint4 bw[2][6];
#pragma unroll
    for (int nt = 0; nt < 2; ++nt) {
      const int nrow = wv * 32 + nt * 16 + m16;
#pragma unroll
      for (int j = 0; j < 6; ++j) {
        const int ks = kh * 6 + j;
        bw[nt][j] = *(const uint4*)(w2T + (size_t)nrow * HIDDEN + ks * 32 + quad * 8);
      }
    }
#pragma unroll 1
    for (int mt = 0; mt < 4; ++mt) {
      uint4 afr[6];
#pragma unroll
      for (int j = 0; j < 6; ++j) {
        const int cc = (kh * 6 + j) * 4 + quad;  // chunk 0..47
        afr[j] = *(const uint4*)(sb + 16384 + (mt * 16 + m16) * 768 + ((cc ^ m7) << 4));
      }
#pragma unroll
      for (int j = 0; j < 6; ++j) {
        const bf16x8 a = as_bf(afr[j]);
        acc[mt][0] =
            __builtin_amdgcn_mfma_f32_16x16x32_bf16(a, as_bf(bw[0][j]), acc[mt][0], 0, 0, 0);
        acc[mt][1] =
            __builtin_amdgcn_mfma_f32_16x16x32_bf16(a, as_bf(bw[1][j]), acc[mt][1], 0, 0, 0);
      }
    }
  }

#pragma unroll
  for (int mt = 0; mt < 4; ++mt) {
#pragma unroll
    for (int nt = 0; nt < 2; ++nt) {
      const int col = wv * 32 + nt * 16 + m16;
#pragma unroll
      for (int r = 0; r < 4; ++r) {
        const int rowg = row0 + mt * 16 + quad * 4 + r;
        const size_t idx = (size_t)rowg * DIM + col;
        const float val = acc[mt][nt][r] + xin[idx];
        xout[idx] = do_tanh ? tanhf(val) : val;
      }
    }
  }
}

// ---------------------------------------------------------------------------
// readout: out[row] = dot(fbuf[row], wout) + bout   (one wave per row)
// ---------------------------------------------------------------------------
__global__ __launch_bounds__(256) void readout_kernel(const float* __restrict__ fbuf,
                                                      const float* __restrict__ wout,
                                                      const float* __restrict__ bout,
                                                      float* __restrict__ out) {
  const int t = threadIdx.x;
  const int row = blockIdx.x * 4 + (t >> 6);
  const int lane = t & 63;
  const float2 f = *(const float2*)(fbuf + (size_t)row * DIM + lane * 2);
  const float2 w = *(const float2*)(wout + lane * 2);
  float s = f.x * w.x + f.y * w.y;
  s += __shfl_xor(s, 1);
  s += __shfl_xor(s, 2);
  s += __shfl_xor(s, 4);
  s += __shfl_xor(s, 8);
  s += __shfl_xor(s, 16);
  s += __shfl_xor(s, 32);
  if (lane == 0) out[row] = s + bout[0];
}

// ---------------------------------------------------------------------------
extern "C" void kernel_launch(void* const* d_in, const int* in_sizes, int n_in,
                              void* d_out, int out_size, void* d_ws, size_t ws_size,
                              hipStream_t stream) {
  const float* v = (const float*)d_in[0];
  const int* data_src = (const int*)d_in[1];
  const int* data_dst = (const int*)d_in[2];
  const float* rms1_w = (const float*)d_in[4];
  const float* w1a = (const float*)d_in[5];
  const float* w2a = (const float*)d_in[6];
  const float* w3a = (const float*)d_in[7];
  const float* rms2_w = (const float*)d_in[8];
  const float* w1b = (const float*)d_in[9];
  const float* w2b = (const float*)d_in[10];
  const float* w3b = (const float*)d_in[11];
  const float* wout = (const float*)d_in[12];
  const float* bout = (const float*)d_in[13];
  float* out = (float*)d_out;

  char* ws = (char*)d_ws;
  size_t off = 0;
  auto take = [&](size_t bytes) -> char* {
    char* p = ws + off;
    off += (bytes + 255) & ~(size_t)255;
    return p;
  };
  float* v_act = (float*)take((size_t)BATCH * NDATA * DIM * 4);  // 204.8 MB
  float* lbuf = (float*)take((size_t)BATCH * NLOG * DIM * 4);    // 8.4 MB
  float* fbuf = (float*)take((size_t)BATCH * NLOG * DIM * 4);    // 8.4 MB
  int* counts = (int*)take(NLOG * 4);
  int* offsets = (int*)take((NLOG + 1) * 4);
  int* cursor = (int*)take(NLOG * 4);
  int* sorted_src = (int*)take(NEDGE * 4);
  u16* w1Ta = (u16*)take(HIDDEN * DIM * 2);
  u16* w3Ta = (u16*)take(HIDDEN * DIM * 2);
  u16* w2Ta = (u16*)take(HIDDEN * DIM * 2);
  u16* w1Tb = (u16*)take(HIDDEN * DIM * 2);
  u16* w3Tb = (u16*)take(HIDDEN * DIM * 2);
  u16* w2Tb = (u16*)take(HIDDEN * DIM * 2);

  // weight cast/transpose (tiny)
  convert_w_kernel<<<(HIDDEN * DIM) / 256, 256, 0, stream>>>(
      w1a, w3a, w2a, w1b, w3b, w2b, w1Ta, w3Ta, w2Ta, w1Tb, w3Tb, w2Tb);
  // CSR build
  zero_counts_kernel<<<(NLOG + 255) / 256, 256, 0, stream>>>(counts);
  count_kernel<<<(NEDGE + 255) / 256, 256, 0, stream>>>(data_dst, counts);
  scan_kernel<<<1, 1024, 0, stream>>>(counts, offsets, cursor);
  scatter_kernel<<<(NEDGE + 255) / 256, 256, 0, stream>>>(data_src, data_dst, cursor,
                                                          sorted_src);
  // FFN1 + tanh over 400k rows (MFMA)
  ffn_mfma_kernel<<<(BATCH * NDATA) / 64, 256, 0, stream>>>(v, rms1_w, w1Ta, w3Ta, w2Ta,
                                                            v_act, 1);
  // segment products
  prod_kernel<<<dim3(NLOG, BATCH), 128, 0, stream>>>(v_act, offsets, sorted_src, lbuf);
  // FFN2 (MFMA, no tanh) + readout
  ffn_mfma_kernel<<<(BATCH * NLOG) / 64, 256, 0, stream>>>(lbuf, rms2_w, w1Tb, w3Tb, w2Tb,
                                                           fbuf, 0);
  readout_kernel<<<(BATCH * NLOG) / 4, 256, 0, stream>>>(fbuf, wout, bout, out);
}

// Round 3
// 694.716 us; speedup vs baseline: 3.2101x; 1.1287x over previous
//
#include <hip/hip_runtime.h>
#include <hip/hip_bf16.h>

#define DIM 128
#define HIDDEN 384
#define BATCH 4
#define NDATA 100000
#define NEDGE 200000
#define NLOG 4096

typedef __bf16 bf16x8 __attribute__((ext_vector_type(8)));
typedef float f32x4 __attribute__((ext_vector_type(4)));
typedef unsigned short u16;
typedef unsigned int u32;

__device__ __forceinline__ u16 f2bf(float f) {
  u32 u = __float_as_uint(f);
  u += 0x7FFFu + ((u >> 16) & 1u);  // RNE; values are finite
  return (u16)(u >> 16);
}
__device__ __forceinline__ bf16x8 as_bf(uint4 u) {
  return __builtin_bit_cast(bf16x8, u);
}
// tanh via e^{2x}: ~6 VALU ops; abs err ~1e-7 (<< bf16 path error 1.5e-4)
__device__ __forceinline__ float fast_tanh(float x) {
  float xc = fminf(fmaxf(x, -15.f), 15.f);
  float t = __expf(2.f * xc);
  return (t - 1.f) * __frcp_rn(t + 1.f);
}

// ---------------------------------------------------------------------------
// CSR build: histogram -> scan -> scatter
// ---------------------------------------------------------------------------
__global__ void zero_counts_kernel(int* __restrict__ counts) {
  int i = blockIdx.x * blockDim.x + threadIdx.x;
  if (i < NLOG) counts[i] = 0;
}

__global__ void count_kernel(const int* __restrict__ dst, int* __restrict__ counts) {
  int e = blockIdx.x * blockDim.x + threadIdx.x;
  if (e < NEDGE) atomicAdd(&counts[dst[e]], 1);
}

__global__ __launch_bounds__(1024) void scan_kernel(const int* __restrict__ counts,
                                                    int* __restrict__ offsets,
                                                    int* __restrict__ cursor) {
  __shared__ int sdata[1024];
  const int t = threadIdx.x;
  const int c0 = counts[4 * t + 0];
  const int c1 = counts[4 * t + 1];
  const int c2 = counts[4 * t + 2];
  const int c3 = counts[4 * t + 3];
  const int s = c0 + c1 + c2 + c3;
  sdata[t] = s;
  __syncthreads();
  for (int off = 1; off < 1024; off <<= 1) {
    int vv = (t >= off) ? sdata[t - off] : 0;
    __syncthreads();
    sdata[t] += vv;
    __syncthreads();
  }
  const int excl = sdata[t] - s;
  const int o0 = excl, o1 = o0 + c0, o2 = o1 + c1, o3 = o2 + c2;
  offsets[4 * t + 0] = o0;
  offsets[4 * t + 1] = o1;
  offsets[4 * t + 2] = o2;
  offsets[4 * t + 3] = o3;
  cursor[4 * t + 0] = o0;
  cursor[4 * t + 1] = o1;
  cursor[4 * t + 2] = o2;
  cursor[4 * t + 3] = o3;
  if (t == 1023) offsets[NLOG] = o3 + c3;
}

__global__ void scatter_kernel(const int* __restrict__ src, const int* __restrict__ dst,
                               int* __restrict__ cursor, int* __restrict__ sorted_src) {
  int e = blockIdx.x * blockDim.x + threadIdx.x;
  if (e < NEDGE) {
    int d = dst[e];
    int pos = atomicAdd(&cursor[d], 1);
    sorted_src[pos] = src[e];
  }
}

// ---------------------------------------------------------------------------
// segment product over transposed v_act [i][b][dim]: one block per segment,
// 512 threads = (batch, dim). Each edge reads 2 KB fully contiguous.
// ---------------------------------------------------------------------------
__global__ __launch_bounds__(512) void prod_kernel_t(const float* __restrict__ va,
                                                     const int* __restrict__ offsets,
                                                     const int* __restrict__ sorted_src,
                                                     float* __restrict__ l) {
  const int s = blockIdx.x;
  const int t = threadIdx.x;  // t = b*128 + d
  const int beg = offsets[s];
  const int end = offsets[s + 1];
  const float* base = va + t;
  float p0 = 1.f, p1 = 1.f, p2 = 1.f, p3 = 1.f;
  int e = beg;
  for (; e + 4 <= end; e += 4) {
    const int i0 = sorted_src[e + 0];
    const int i1 = sorted_src[e + 1];
    const int i2 = sorted_src[e + 2];
    const int i3 = sorted_src[e + 3];
    p0 *= base[(size_t)i0 * 512];
    p1 *= base[(size_t)i1 * 512];
    p2 *= base[(size_t)i2 * 512];
    p3 *= base[(size_t)i3 * 512];
  }
  for (; e < end; ++e) p0 *= base[(size_t)sorted_src[e] * 512];
  l[((size_t)(t >> 7) * NLOG + s) * DIM + (t & 127)] = (p0 * p1) * (p2 * p3);
}

// ---------------------------------------------------------------------------
// weight convert: fp32 -> bf16, transposed to [N][K] (K contiguous)
// ---------------------------------------------------------------------------
__global__ __launch_bounds__(256) void convert_w_kernel(
    const float* __restrict__ w1a, const float* __restrict__ w3a,
    const float* __restrict__ w2a, const float* __restrict__ w1b,
    const float* __restrict__ w3b, const float* __restrict__ w2b,
    u16* __restrict__ w1Ta, u16* __restrict__ w3Ta, u16* __restrict__ w2Ta,
    u16* __restrict__ w1Tb, u16* __restrict__ w3Tb, u16* __restrict__ w2Tb) {
  const int i = blockIdx.x * 256 + threadIdx.x;  // 0..49151 exact
  const int n1 = i >> 7, k1 = i & 127;           // w1T/w3T: [384][128]
  w1Ta[i] = f2bf(w1a[k1 * HIDDEN + n1]);
  w3Ta[i] = f2bf(w3a[k1 * HIDDEN + n1]);
  w1Tb[i] = f2bf(w1b[k1 * HIDDEN + n1]);
  w3Tb[i] = f2bf(w3b[k1 * HIDDEN + n1]);
  const int n2 = i / HIDDEN, k2 = i - n2 * HIDDEN;  // w2T: [128][384]
  w2Ta[i] = f2bf(w2a[k2 * DIM + n2]);
  w2Tb[i] = f2bf(w2b[k2 * DIM + n2]);
}

// ---------------------------------------------------------------------------
// Fused MFMA FFN, transposed GEMMs: D = W^T (A, from global) x X^T (B, LDS).
// C/D layout (m89): col=lane&15 = data row, row=quad*4+r = output feature ->
// 4 CONSECUTIVE features per lane: b64 gs spills, float4 epilogue.
// 64 rows/block, 4 waves; GEMM1 waves partition hidden (96 each);
// GEMM2 waves partition out-dim (32 each). LDS 64 KB: xn 16K + gs 48K,
// 16B-chunk XOR-(row&7) swizzle everywhere (2-way worst = free, m136).
// mode: 1 = ffn1 (tanh + transposed [i][b][dim] store), 0 = ffn2 (flat).
// ---------------------------------------------------------------------------
__global__ __launch_bounds__(256, 2) void ffn_mfma_kernel(
    const float* __restrict__ xin, const float* __restrict__ rmsw,
    const u16* __restrict__ w1T, const u16* __restrict__ w3T,
    const u16* __restrict__ w2T, float* __restrict__ xout, int mode) {
  __shared__ alignas(16) u16 sm[32768];  // 65536 B: xn @0 (16K), gs @16384 (48K)
  char* const sb = (char*)sm;
  const int t = threadIdx.x;
  const int row0 = blockIdx.x * 64;

  // ---- Phase A: load + rmsnorm -> xn (bf16, swizzled 16B chunks) ----
  {
    const int r = t >> 2;  // 0..63
    const int q = t & 3;   // 32-col slice
    const float* vr = xin + (size_t)(row0 + r) * DIM + q * 32;
    float av[32];
#pragma unroll
    for (int i = 0; i < 8; ++i) *(float4*)(av + 4 * i) = *(const float4*)(vr + 4 * i);
    float ss = 0.f;
#pragma unroll
    for (int i = 0; i < 32; ++i) ss += av[i] * av[i];
    ss += __shfl_xor(ss, 1);
    ss += __shfl_xor(ss, 2);
    const float scale = rsqrtf(ss * (1.0f / DIM) + 1e-5f);
    const int r7 = r & 7;
#pragma unroll
    for (int i = 0; i < 4; ++i) {
      u16 us[8];
#pragma unroll
      for (int j = 0; j < 8; ++j)
        us[j] = f2bf(av[8 * i + j] * scale * rmsw[q * 32 + 8 * i + j]);
      uint4 pk;
      pk.x = (u32)us[0] | ((u32)us[1] << 16);
      pk.y = (u32)us[2] | ((u32)us[3] << 16);
      pk.z = (u32)us[4] | ((u32)us[5] << 16);
      pk.w = (u32)us[6] | ((u32)us[7] << 16);
      const int c = q * 4 + i;
      *(uint4*)(sb + r * 256 + ((c ^ r7) << 4)) = pk;
    }
  }
  __syncthreads();

  const int wv = t >> 6;
  const int lane = t & 63;
  const int m16 = lane & 15;
  const int quad = lane >> 4;
  const int m7 = m16 & 7;

  // ---- B-fragments (xn) hoisted once: all 64 rows x K=128 ----
  uint4 bfr[4][4];
#pragma unroll
  for (int nt = 0; nt < 4; ++nt) {
    const int row = nt * 16 + m16;
#pragma unroll
    for (int ks = 0; ks < 4; ++ks)
      bfr[nt][ks] = *(const uint4*)(sb + row * 256 + (((4 * ks + quad) ^ m7) << 4));
  }

  // ---- GEMM1: H^T = {W1,W3}^T @ X^T; gs = silu(h1)*h3 -> LDS (b64) ----
  const int woff = wv * 96;  // this wave's hidden slice
#pragma unroll 1
  for (int mt = 0; mt < 6; ++mt) {
    const size_t wrow = (size_t)(woff + mt * 16 + m16) * DIM + quad * 8;
    uint4 a1[4], a3[4];
#pragma unroll
    for (int ks = 0; ks < 4; ++ks) {
      a1[ks] = *(const uint4*)(w1T + wrow + ks * 32);
      a3[ks] = *(const uint4*)(w3T + wrow + ks * 32);
    }
    f32x4 acc1[4] = {{0.f, 0.f, 0.f, 0.f}, {0.f, 0.f, 0.f, 0.f},
                     {0.f, 0.f, 0.f, 0.f}, {0.f, 0.f, 0.f, 0.f}};
    f32x4 acc3[4] = {{0.f, 0.f, 0.f, 0.f}, {0.f, 0.f, 0.f, 0.f},
                     {0.f, 0.f, 0.f, 0.f}, {0.f, 0.f, 0.f, 0.f}};
#pragma unroll
    for (int ks = 0; ks < 4; ++ks) {
      const bf16x8 fa1 = as_bf(a1[ks]);
      const bf16x8 fa3 = as_bf(a3[ks]);
#pragma unroll
      for (int nt = 0; nt < 4; ++nt) {
        const bf16x8 fb = as_bf(bfr[nt][ks]);
        acc1[nt] = __builtin_amdgcn_mfma_f32_16x16x32_bf16(fa1, fb, acc1[nt], 0, 0, 0);
        acc3[nt] = __builtin_amdgcn_mfma_f32_16x16x32_bf16(fa3, fb, acc3[nt], 0, 0, 0);
      }
    }
    // epilogue: lane holds 4 consecutive hidden (h0..h0+3) at 4 rows (nt)
    const int hch = (woff + mt * 16) >> 3;  // even chunk base
    const int chu = (hch + (quad >> 1));
    const int half = (quad & 1) * 8;
#pragma unroll
    for (int nt = 0; nt < 4; ++nt) {
      const int row = nt * 16 + m16;
      u16 g[4];
#pragma unroll
      for (int r = 0; r < 4; ++r) {
        const float h1 = acc1[nt][r], h3 = acc3[nt][r];
        g[r] = f2bf(h1 * (1.0f / (1.0f + __expf(-h1))) * h3);
      }
      uint2 pk;
      pk.x = (u32)g[0] | ((u32)g[1] << 16);
      pk.y = (u32)g[2] | ((u32)g[3] << 16);
      *(uint2*)(sb + 16384 + row * 768 + ((chu ^ m7) << 4) + half) = pk;
    }
  }
  __syncthreads();

  // ---- GEMM2: F^T = W2^T @ G^T (+residual, mode-dependent store) ----
#pragma unroll 1
  for (int nt = 0; nt < 4; ++nt) {
    const int row = nt * 16 + m16;
    uint4 bg[12];
#pragma unroll
    for (int ks = 0; ks < 12; ++ks)
      bg[ks] = *(const uint4*)(sb + 16384 + row * 768 + (((4 * ks + quad) ^ m7) << 4));
    const int grow = row0 + row;
#pragma unroll
    for (int mt = 0; mt < 2; ++mt) {
      const size_t wrow = (size_t)(wv * 32 + mt * 16 + m16) * HIDDEN + quad * 8;
      uint4 aw[12];
#pragma unroll
      for (int ks = 0; ks < 12; ++ks) aw[ks] = *(const uint4*)(w2T + wrow + ks * 32);
      f32x4 acc = {0.f, 0.f, 0.f, 0.f};
#pragma unroll
      for (int ks = 0; ks < 12; ++ks)
        acc = __builtin_amdgcn_mfma_f32_16x16x32_bf16(as_bf(aw[ks]), as_bf(bg[ks]), acc,
                                                      0, 0, 0);
      const int d0 = wv * 32 + mt * 16 + quad * 4;
      const float4 res = *(const float4*)(xin + (size_t)grow * DIM + d0);
      float4 o;
      o.x = acc[0] + res.x;
      o.y = acc[1] + res.y;
      o.z = acc[2] + res.z;
      o.w = acc[3] + res.w;
      if (mode) {  // ffn1: tanh + transposed store [i][b][dim]
        o.x = fast_tanh(o.x);
        o.y = fast_tanh(o.y);
        o.z = fast_tanh(o.z);
        o.w = fast_tanh(o.w);
        const int b = grow / NDATA;
        const int i = grow - b * NDATA;
        *(float4*)(xout + ((size_t)i * BATCH + b) * DIM + d0) = o;
      } else {
        *(float4*)(xout + (size_t)grow * DIM + d0) = o;
      }
    }
  }
}

// ---------------------------------------------------------------------------
// readout: out[row] = dot(fbuf[row], wout) + bout
// ---------------------------------------------------------------------------
__global__ __launch_bounds__(256) void readout_kernel(const float* __restrict__ fbuf,
                                                      const float* __restrict__ wout,
                                                      const float* __restrict__ bout,
                                                      float* __restrict__ out) {
  const int t = threadIdx.x;
  const int row = blockIdx.x * 4 + (t >> 6);
  const int lane = t & 63;
  const float2 f = *(const float2*)(fbuf + (size_t)row * DIM + lane * 2);
  const float2 w = *(const float2*)(wout + lane * 2);
  float s = f.x * w.x + f.y * w.y;
  s += __shfl_xor(s, 1);
  s += __shfl_xor(s, 2);
  s += __shfl_xor(s, 4);
  s += __shfl_xor(s, 8);
  s += __shfl_xor(s, 16);
  s += __shfl_xor(s, 32);
  if (lane == 0) out[row] = s + bout[0];
}

// ---------------------------------------------------------------------------
extern "C" void kernel_launch(void* const* d_in, const int* in_sizes, int n_in,
                              void* d_out, int out_size, void* d_ws, size_t ws_size,
                              hipStream_t stream) {
  const float* v = (const float*)d_in[0];
  const int* data_src = (const int*)d_in[1];
  const int* data_dst = (const int*)d_in[2];
  const float* rms1_w = (const float*)d_in[4];
  const float* w1a = (const float*)d_in[5];
  const float* w2a = (const float*)d_in[6];
  const float* w3a = (const float*)d_in[7];
  const float* rms2_w = (const float*)d_in[8];
  const float* w1b = (const float*)d_in[9];
  const float* w2b = (const float*)d_in[10];
  const float* w3b = (const float*)d_in[11];
  const float* wout = (const float*)d_in[12];
  const float* bout = (const float*)d_in[13];
  float* out = (float*)d_out;

  char* ws = (char*)d_ws;
  size_t off = 0;
  auto take = [&](size_t bytes) -> char* {
    char* p = ws + off;
    off += (bytes + 255) & ~(size_t)255;
    return p;
  };
  float* v_act_t = (float*)take((size_t)BATCH * NDATA * DIM * 4);  // [i][b][dim]
  float* lbuf = (float*)take((size_t)BATCH * NLOG * DIM * 4);
  float* fbuf = (float*)take((size_t)BATCH * NLOG * DIM * 4);
  int* counts = (int*)take(NLOG * 4);
  int* offsets = (int*)take((NLOG + 1) * 4);
  int* cursor = (int*)take(NLOG * 4);
  int* sorted_src = (int*)take(NEDGE * 4);
  u16* w1Ta = (u16*)take(HIDDEN * DIM * 2);
  u16* w3Ta = (u16*)take(HIDDEN * DIM * 2);
  u16* w2Ta = (u16*)take(HIDDEN * DIM * 2);
  u16* w1Tb = (u16*)take(HIDDEN * DIM * 2);
  u16* w3Tb = (u16*)take(HIDDEN * DIM * 2);
  u16* w2Tb = (u16*)take(HIDDEN * DIM * 2);

  convert_w_kernel<<<(HIDDEN * DIM) / 256, 256, 0, stream>>>(
      w1a, w3a, w2a, w1b, w3b, w2b, w1Ta, w3Ta, w2Ta, w1Tb, w3Tb, w2Tb);
  zero_counts_kernel<<<(NLOG + 255) / 256, 256, 0, stream>>>(counts);
  count_kernel<<<(NEDGE + 255) / 256, 256, 0, stream>>>(data_dst, counts);
  scan_kernel<<<1, 1024, 0, stream>>>(counts, offsets, cursor);
  scatter_kernel<<<(NEDGE + 255) / 256, 256, 0, stream>>>(data_src, data_dst, cursor,
                                                          sorted_src);
  // FFN1 + tanh over 400k rows -> transposed v_act
  ffn_mfma_kernel<<<(BATCH * NDATA) / 64, 256, 0, stream>>>(v, rms1_w, w1Ta, w3Ta, w2Ta,
                                                            v_act_t, 1);
  // segment products over transposed layout
  prod_kernel_t<<<NLOG, 512, 0, stream>>>(v_act_t, offsets, sorted_src, lbuf);
  // FFN2 (flat) + readout
  ffn_mfma_kernel<<<(BATCH * NLOG) / 64, 256, 0, stream>>>(lbuf, rms2_w, w1Tb, w3Tb, w2Tb,
                                                           fbuf, 0);
  readout_kernel<<<(BATCH * NLOG) / 4, 256, 0, stream>>>(fbuf, wout, bout, out);
}

// Round 4
// 678.424 us; speedup vs baseline: 3.2872x; 1.0240x over previous
//
#include <hip/hip_runtime.h>
#include <hip/hip_bf16.h>

#define DIM 128
#define HIDDEN 384
#define BATCH 4
#define NDATA 100000
#define NEDGE 200000
#define NLOG 4096

typedef __bf16 bf16x8 __attribute__((ext_vector_type(8)));
typedef float f32x4 __attribute__((ext_vector_type(4)));
typedef unsigned short u16;
typedef unsigned int u32;

__device__ __forceinline__ u16 f2bf(float f) {
  u32 u = __float_as_uint(f);
  u += 0x7FFFu + ((u >> 16) & 1u);  // RNE; values are finite
  return (u16)(u >> 16);
}
__device__ __forceinline__ bf16x8 as_bf(uint4 u) {
  return __builtin_bit_cast(bf16x8, u);
}
// tanh via e^{2x}: ~6 VALU ops; abs err ~1e-7 (<< bf16 path error 1.5e-4)
__device__ __forceinline__ float fast_tanh(float x) {
  float xc = fminf(fmaxf(x, -15.f), 15.f);
  float t = __expf(2.f * xc);
  return (t - 1.f) * __frcp_rn(t + 1.f);
}

// ---------------------------------------------------------------------------
// CSR build: histogram -> scan -> scatter
// ---------------------------------------------------------------------------
__global__ void zero_counts_kernel(int* __restrict__ counts) {
  int i = blockIdx.x * blockDim.x + threadIdx.x;
  if (i < NLOG) counts[i] = 0;
}

__global__ void count_kernel(const int* __restrict__ dst, int* __restrict__ counts) {
  int e = blockIdx.x * blockDim.x + threadIdx.x;
  if (e < NEDGE) atomicAdd(&counts[dst[e]], 1);
}

__global__ __launch_bounds__(1024) void scan_kernel(const int* __restrict__ counts,
                                                    int* __restrict__ offsets,
                                                    int* __restrict__ cursor) {
  __shared__ int sdata[1024];
  const int t = threadIdx.x;
  const int c0 = counts[4 * t + 0];
  const int c1 = counts[4 * t + 1];
  const int c2 = counts[4 * t + 2];
  const int c3 = counts[4 * t + 3];
  const int s = c0 + c1 + c2 + c3;
  sdata[t] = s;
  __syncthreads();
  for (int off = 1; off < 1024; off <<= 1) {
    int vv = (t >= off) ? sdata[t - off] : 0;
    __syncthreads();
    sdata[t] += vv;
    __syncthreads();
  }
  const int excl = sdata[t] - s;
  const int o0 = excl, o1 = o0 + c0, o2 = o1 + c1, o3 = o2 + c2;
  offsets[4 * t + 0] = o0;
  offsets[4 * t + 1] = o1;
  offsets[4 * t + 2] = o2;
  offsets[4 * t + 3] = o3;
  cursor[4 * t + 0] = o0;
  cursor[4 * t + 1] = o1;
  cursor[4 * t + 2] = o2;
  cursor[4 * t + 3] = o3;
  if (t == 1023) offsets[NLOG] = o3 + c3;
}

__global__ void scatter_kernel(const int* __restrict__ src, const int* __restrict__ dst,
                               int* __restrict__ cursor, int* __restrict__ sorted_src) {
  int e = blockIdx.x * blockDim.x + threadIdx.x;
  if (e < NEDGE) {
    int d = dst[e];
    int pos = atomicAdd(&cursor[d], 1);
    sorted_src[pos] = src[e];
  }
}

// ---------------------------------------------------------------------------
// segment product over transposed v_act [i][b][dim]: one block per segment,
// 512 threads = (batch, dim); 8 independent chains to cover load latency.
// ---------------------------------------------------------------------------
__global__ __launch_bounds__(512) void prod_kernel_t(const float* __restrict__ va,
                                                     const int* __restrict__ offsets,
                                                     const int* __restrict__ sorted_src,
                                                     float* __restrict__ l) {
  const int s = blockIdx.x;
  const int t = threadIdx.x;  // t = b*128 + d
  const int beg = offsets[s];
  const int end = offsets[s + 1];
  const float* base = va + t;
  float p[8];
#pragma unroll
  for (int i = 0; i < 8; ++i) p[i] = 1.f;
  int e = beg;
  for (; e + 8 <= end; e += 8) {
#pragma unroll
    for (int i = 0; i < 8; ++i) p[i] *= base[(size_t)sorted_src[e + i] * 512];
  }
  for (; e < end; ++e) p[0] *= base[(size_t)sorted_src[e] * 512];
  const float r = ((p[0] * p[1]) * (p[2] * p[3])) * ((p[4] * p[5]) * (p[6] * p[7]));
  l[((size_t)(t >> 7) * NLOG + s) * DIM + (t & 127)] = r;
}

// ---------------------------------------------------------------------------
// weight convert: fp32 -> bf16, transposed to [N][K] (K contiguous)
// ---------------------------------------------------------------------------
__global__ __launch_bounds__(256) void convert_w_kernel(
    const float* __restrict__ w1a, const float* __restrict__ w3a,
    const float* __restrict__ w2a, const float* __restrict__ w1b,
    const float* __restrict__ w3b, const float* __restrict__ w2b,
    u16* __restrict__ w1Ta, u16* __restrict__ w3Ta, u16* __restrict__ w2Ta,
    u16* __restrict__ w1Tb, u16* __restrict__ w3Tb, u16* __restrict__ w2Tb) {
  const int i = blockIdx.x * 256 + threadIdx.x;  // 0..49151 exact
  const int n1 = i >> 7, k1 = i & 127;           // w1T/w3T: [384][128]
  w1Ta[i] = f2bf(w1a[k1 * HIDDEN + n1]);
  w3Ta[i] = f2bf(w3a[k1 * HIDDEN + n1]);
  w1Tb[i] = f2bf(w1b[k1 * HIDDEN + n1]);
  w3Tb[i] = f2bf(w3b[k1 * HIDDEN + n1]);
  const int n2 = i / HIDDEN, k2 = i - n2 * HIDDEN;  // w2T: [128][384]
  w2Ta[i] = f2bf(w2a[k2 * DIM + n2]);
  w2Tb[i] = f2bf(w2b[k2 * DIM + n2]);
}

// ---------------------------------------------------------------------------
// Fused MFMA FFN, transposed GEMMs: D = W^T (A, global) x X^T (B, LDS).
// LDS = 48 KB: xn[64][128]bf16 lives in [0,16K) ONLY until all waves hoist
// B-fragments to registers; after a barrier, gs[64][384]bf16 reuses [0,48K).
// 48 KB -> 3 blocks/CU (was 64 KB -> 2): the round-4 occupancy lever.
// GEMM2 is mt-outer so w2 A-frags load once per mt (was 4x redundant).
// Swizzle: physical 16B chunk = logical ^ (row&7) on both write & read.
// mode: 1 = ffn1 (tanh + transposed [i][b][dim] store), 0 = ffn2 (flat).
// ---------------------------------------------------------------------------
__global__ __launch_bounds__(256, 3) void ffn_mfma_kernel(
    const float* __restrict__ xin, const float* __restrict__ rmsw,
    const u16* __restrict__ w1T, const u16* __restrict__ w3T,
    const u16* __restrict__ w2T, float* __restrict__ xout, int mode) {
  __shared__ alignas(16) u16 sm[24576];  // 49152 B
  char* const sb = (char*)sm;
  const int t = threadIdx.x;
  const int row0 = blockIdx.x * 64;

  // ---- Phase A: load + rmsnorm -> xn (bf16, swizzled 16B chunks) ----
  {
    const int r = t >> 2;  // 0..63
    const int q = t & 3;   // 32-col slice
    const float* vr = xin + (size_t)(row0 + r) * DIM + q * 32;
    float av[32];
#pragma unroll
    for (int i = 0; i < 8; ++i) *(float4*)(av + 4 * i) = *(const float4*)(vr + 4 * i);
    float ss = 0.f;
#pragma unroll
    for (int i = 0; i < 32; ++i) ss += av[i] * av[i];
    ss += __shfl_xor(ss, 1);
    ss += __shfl_xor(ss, 2);
    const float scale = rsqrtf(ss * (1.0f / DIM) + 1e-5f);
    const int r7 = r & 7;
#pragma unroll
    for (int i = 0; i < 4; ++i) {
      u16 us[8];
#pragma unroll
      for (int j = 0; j < 8; ++j)
        us[j] = f2bf(av[8 * i + j] * scale * rmsw[q * 32 + 8 * i + j]);
      uint4 pk;
      pk.x = (u32)us[0] | ((u32)us[1] << 16);
      pk.y = (u32)us[2] | ((u32)us[3] << 16);
      pk.z = (u32)us[4] | ((u32)us[5] << 16);
      pk.w = (u32)us[6] | ((u32)us[7] << 16);
      const int c = q * 4 + i;
      *(uint4*)(sb + r * 256 + ((c ^ r7) << 4)) = pk;
    }
  }
  __syncthreads();

  const int wv = t >> 6;
  const int lane = t & 63;
  const int m16 = lane & 15;
  const int quad = lane >> 4;
  const int m7 = m16 & 7;

  // ---- B-fragments (xn) hoisted once: all 64 rows x K=128 ----
  uint4 bfr[4][4];
#pragma unroll
  for (int nt = 0; nt < 4; ++nt) {
    const int row = nt * 16 + m16;
#pragma unroll
    for (int ks = 0; ks < 4; ++ks)
      bfr[nt][ks] = *(const uint4*)(sb + row * 256 + (((4 * ks + quad) ^ m7) << 4));
  }
  __syncthreads();  // xn region is now dead; gs may alias it

  // ---- GEMM1: H^T = {W1,W3}^T @ X^T; gs = silu(h1)*h3 -> LDS (b64) ----
  const int woff = wv * 96;  // this wave's hidden slice
#pragma unroll 1
  for (int mt = 0; mt < 6; ++mt) {
    const size_t wrow = (size_t)(woff + mt * 16 + m16) * DIM + quad * 8;
    uint4 a1[4], a3[4];
#pragma unroll
    for (int ks = 0; ks < 4; ++ks) {
      a1[ks] = *(const uint4*)(w1T + wrow + ks * 32);
      a3[ks] = *(const uint4*)(w3T + wrow + ks * 32);
    }
    f32x4 acc1[4] = {{0.f, 0.f, 0.f, 0.f}, {0.f, 0.f, 0.f, 0.f},
                     {0.f, 0.f, 0.f, 0.f}, {0.f, 0.f, 0.f, 0.f}};
    f32x4 acc3[4] = {{0.f, 0.f, 0.f, 0.f}, {0.f, 0.f, 0.f, 0.f},
                     {0.f, 0.f, 0.f, 0.f}, {0.f, 0.f, 0.f, 0.f}};
#pragma unroll
    for (int ks = 0; ks < 4; ++ks) {
      const bf16x8 fa1 = as_bf(a1[ks]);
      const bf16x8 fa3 = as_bf(a3[ks]);
#pragma unroll
      for (int nt = 0; nt < 4; ++nt) {
        const bf16x8 fb = as_bf(bfr[nt][ks]);
        acc1[nt] = __builtin_amdgcn_mfma_f32_16x16x32_bf16(fa1, fb, acc1[nt], 0, 0, 0);
        acc3[nt] = __builtin_amdgcn_mfma_f32_16x16x32_bf16(fa3, fb, acc3[nt], 0, 0, 0);
      }
    }
    // epilogue: lane holds 4 consecutive hidden (h0..h0+3) at 4 rows (nt)
    const int hch = (woff + mt * 16) >> 3;  // even chunk base
    const int chu = (hch + (quad >> 1));
    const int half = (quad & 1) * 8;
#pragma unroll
    for (int nt = 0; nt < 4; ++nt) {
      const int row = nt * 16 + m16;
      u16 g[4];
#pragma unroll
      for (int r = 0; r < 4; ++r) {
        const float h1 = acc1[nt][r], h3 = acc3[nt][r];
        g[r] = f2bf(h1 * (1.0f / (1.0f + __expf(-h1))) * h3);
      }
      uint2 pk;
      pk.x = (u32)g[0] | ((u32)g[1] << 16);
      pk.y = (u32)g[2] | ((u32)g[3] << 16);
      *(uint2*)(sb + row * 768 + ((chu ^ m7) << 4) + half) = pk;
    }
  }
  __syncthreads();

  // ---- GEMM2: F^T = W2^T @ G^T (+residual); w2 A-frags loaded once per mt ----
#pragma unroll 1
  for (int mt = 0; mt < 2; ++mt) {
    const size_t wrow = (size_t)(wv * 32 + mt * 16 + m16) * HIDDEN + quad * 8;
    uint4 aw[12];
#pragma unroll
    for (int ks = 0; ks < 12; ++ks) aw[ks] = *(const uint4*)(w2T + wrow + ks * 32);
#pragma unroll 1
    for (int nt = 0; nt < 4; ++nt) {
      const int row = nt * 16 + m16;
      uint4 bg[12];
#pragma unroll
      for (int ks = 0; ks < 12; ++ks)
        bg[ks] = *(const uint4*)(sb + row * 768 + (((4 * ks + quad) ^ m7) << 4));
      f32x4 acc = {0.f, 0.f, 0.f, 0.f};
#pragma unroll
      for (int ks = 0; ks < 12; ++ks)
        acc = __builtin_amdgcn_mfma_f32_16x16x32_bf16(as_bf(aw[ks]), as_bf(bg[ks]), acc,
                                                      0, 0, 0);
      const int grow = row0 + row;
      const int d0 = wv * 32 + mt * 16 + quad * 4;
      const float4 res = *(const float4*)(xin + (size_t)grow * DIM + d0);
      float4 o;
      o.x = acc[0] + res.x;
      o.y = acc[1] + res.y;
      o.z = acc[2] + res.z;
      o.w = acc[3] + res.w;
      if (mode) {  // ffn1: tanh + transposed store [i][b][dim]
        o.x = fast_tanh(o.x);
        o.y = fast_tanh(o.y);
        o.z = fast_tanh(o.z);
        o.w = fast_tanh(o.w);
        const int b = grow / NDATA;
        const int i = grow - b * NDATA;
        *(float4*)(xout + ((size_t)i * BATCH + b) * DIM + d0) = o;
      } else {
        *(float4*)(xout + (size_t)grow * DIM + d0) = o;
      }
    }
  }
}

// ---------------------------------------------------------------------------
// readout: out[row] = dot(fbuf[row], wout) + bout
// ---------------------------------------------------------------------------
__global__ __launch_bounds__(256) void readout_kernel(const float* __restrict__ fbuf,
                                                      const float* __restrict__ wout,
                                                      const float* __restrict__ bout,
                                                      float* __restrict__ out) {
  const int t = threadIdx.x;
  const int row = blockIdx.x * 4 + (t >> 6);
  const int lane = t & 63;
  const float2 f = *(const float2*)(fbuf + (size_t)row * DIM + lane * 2);
  const float2 w = *(const float2*)(wout + lane * 2);
  float s = f.x * w.x + f.y * w.y;
  s += __shfl_xor(s, 1);
  s += __shfl_xor(s, 2);
  s += __shfl_xor(s, 4);
  s += __shfl_xor(s, 8);
  s += __shfl_xor(s, 16);
  s += __shfl_xor(s, 32);
  if (lane == 0) out[row] = s + bout[0];
}

// ---------------------------------------------------------------------------
extern "C" void kernel_launch(void* const* d_in, const int* in_sizes, int n_in,
                              void* d_out, int out_size, void* d_ws, size_t ws_size,
                              hipStream_t stream) {
  const float* v = (const float*)d_in[0];
  const int* data_src = (const int*)d_in[1];
  const int* data_dst = (const int*)d_in[2];
  const float* rms1_w = (const float*)d_in[4];
  const float* w1a = (const float*)d_in[5];
  const float* w2a = (const float*)d_in[6];
  const float* w3a = (const float*)d_in[7];
  const float* rms2_w = (const float*)d_in[8];
  const float* w1b = (const float*)d_in[9];
  const float* w2b = (const float*)d_in[10];
  const float* w3b = (const float*)d_in[11];
  const float* wout = (const float*)d_in[12];
  const float* bout = (const float*)d_in[13];
  float* out = (float*)d_out;

  char* ws = (char*)d_ws;
  size_t off = 0;
  auto take = [&](size_t bytes) -> char* {
    char* p = ws + off;
    off += (bytes + 255) & ~(size_t)255;
    return p;
  };
  float* v_act_t = (float*)take((size_t)BATCH * NDATA * DIM * 4);  // [i][b][dim]
  float* lbuf = (float*)take((size_t)BATCH * NLOG * DIM * 4);
  float* fbuf = (float*)take((size_t)BATCH * NLOG * DIM * 4);
  int* counts = (int*)take(NLOG * 4);
  int* offsets = (int*)take((NLOG + 1) * 4);
  int* cursor = (int*)take(NLOG * 4);
  int* sorted_src = (int*)take(NEDGE * 4);
  u16* w1Ta = (u16*)take(HIDDEN * DIM * 2);
  u16* w3Ta = (u16*)take(HIDDEN * DIM * 2);
  u16* w2Ta = (u16*)take(HIDDEN * DIM * 2);
  u16* w1Tb = (u16*)take(HIDDEN * DIM * 2);
  u16* w3Tb = (u16*)take(HIDDEN * DIM * 2);
  u16* w2Tb = (u16*)take(HIDDEN * DIM * 2);

  convert_w_kernel<<<(HIDDEN * DIM) / 256, 256, 0, stream>>>(
      w1a, w3a, w2a, w1b, w3b, w2b, w1Ta, w3Ta, w2Ta, w1Tb, w3Tb, w2Tb);
  zero_counts_kernel<<<(NLOG + 255) / 256, 256, 0, stream>>>(counts);
  count_kernel<<<(NEDGE + 255) / 256, 256, 0, stream>>>(data_dst, counts);
  scan_kernel<<<1, 1024, 0, stream>>>(counts, offsets, cursor);
  scatter_kernel<<<(NEDGE + 255) / 256, 256, 0, stream>>>(data_src, data_dst, cursor,
                                                          sorted_src);
  // FFN1 + tanh over 400k rows -> transposed v_act
  ffn_mfma_kernel<<<(BATCH * NDATA) / 64, 256, 0, stream>>>(v, rms1_w, w1Ta, w3Ta, w2Ta,
                                                            v_act_t, 1);
  // segment products over transposed layout
  prod_kernel_t<<<NLOG, 512, 0, stream>>>(v_act_t, offsets, sorted_src, lbuf);
  // FFN2 (flat) + readout
  ffn_mfma_kernel<<<(BATCH * NLOG) / 64, 256, 0, stream>>>(lbuf, rms2_w, w1Tb, w3Tb, w2Tb,
                                                           fbuf, 0);
  readout_kernel<<<(BATCH * NLOG) / 4, 256, 0, stream>>>(fbuf, wout, bout, out);
}